// Round 1
// baseline (1231.608 us; speedup 1.0000x reference)
//
#include <hip/hip_runtime.h>
#include <math.h>

#define NF   1024
#define NB   2048
#define DIM  2048
#define NC   1000
#define IMG  150528   // 3*224*224
#define KSEL 8

// ---------------- norms: 1/max(||row||,eps) for feats and bank ----------------
__global__ __launch_bounds__(256) void norms_kernel(
    const float* __restrict__ feats, const float* __restrict__ bank,
    float* __restrict__ invf, float* __restrict__ invb)
{
    int row = blockIdx.x;
    const float* src;
    float* dst;
    if (row < NF) { src = feats + (size_t)row * DIM; dst = invf + row; }
    else          { src = bank  + (size_t)(row - NF) * DIM; dst = invb + (row - NF); }

    float s = 0.f;
    for (int c = threadIdx.x; c < DIM / 4; c += 256) {
        float4 v = ((const float4*)src)[c];
        s += v.x * v.x + v.y * v.y + v.z * v.z + v.w * v.w;
    }
    __shared__ float red[4];
    for (int off = 32; off; off >>= 1) s += __shfl_down(s, off, 64);
    if ((threadIdx.x & 63) == 0) red[threadIdx.x >> 6] = s;
    __syncthreads();
    if (threadIdx.x == 0) {
        float t = red[0] + red[1] + red[2] + red[3];
        float n = fmaxf(sqrtf(t), 1e-12f);
        *dst = 1.0f / n;
    }
}

// ---------------- dist GEMM: dist[i][j] = 1 - (A_i . B_j) * invf[i] * invb[j] --
#define GBM 128
#define GBN 128
#define GBK 16

__global__ __launch_bounds__(256) void dist_kernel(
    const float* __restrict__ A, const float* __restrict__ B,
    const float* __restrict__ invf, const float* __restrict__ invb,
    float* __restrict__ dist)
{
    __shared__ float As[GBK][GBM];   // k-major
    __shared__ float Bs[GBK][GBN];

    const int tid  = threadIdx.x;
    const int brow = blockIdx.y * GBM;   // over NF
    const int bcol = blockIdx.x * GBN;   // over NB
    const int ty   = tid >> 4;           // 0..15
    const int tx   = tid & 15;           // 0..15

    const int lrow = tid >> 2;           // 0..63
    const int lk   = (tid & 3) * 4;      // 0,4,8,12

    float acc[8][8] = {};

    for (int k0 = 0; k0 < DIM; k0 += GBK) {
        float4 a0 = *(const float4*)(A + (size_t)(brow + lrow)      * DIM + k0 + lk);
        float4 a1 = *(const float4*)(A + (size_t)(brow + lrow + 64) * DIM + k0 + lk);
        float4 b0 = *(const float4*)(B + (size_t)(bcol + lrow)      * DIM + k0 + lk);
        float4 b1 = *(const float4*)(B + (size_t)(bcol + lrow + 64) * DIM + k0 + lk);
        __syncthreads();   // previous iteration's LDS reads done
        As[lk + 0][lrow] = a0.x; As[lk + 1][lrow] = a0.y;
        As[lk + 2][lrow] = a0.z; As[lk + 3][lrow] = a0.w;
        As[lk + 0][lrow + 64] = a1.x; As[lk + 1][lrow + 64] = a1.y;
        As[lk + 2][lrow + 64] = a1.z; As[lk + 3][lrow + 64] = a1.w;
        Bs[lk + 0][lrow] = b0.x; Bs[lk + 1][lrow] = b0.y;
        Bs[lk + 2][lrow] = b0.z; Bs[lk + 3][lrow] = b0.w;
        Bs[lk + 0][lrow + 64] = b1.x; Bs[lk + 1][lrow + 64] = b1.y;
        Bs[lk + 2][lrow + 64] = b1.z; Bs[lk + 3][lrow + 64] = b1.w;
        __syncthreads();

        #pragma unroll
        for (int k = 0; k < GBK; ++k) {
            float4 av0 = *(const float4*)&As[k][ty * 8];
            float4 av1 = *(const float4*)&As[k][ty * 8 + 4];
            float4 bv0 = *(const float4*)&Bs[k][tx * 8];
            float4 bv1 = *(const float4*)&Bs[k][tx * 8 + 4];
            float a[8] = {av0.x, av0.y, av0.z, av0.w, av1.x, av1.y, av1.z, av1.w};
            float b[8] = {bv0.x, bv0.y, bv0.z, bv0.w, bv1.x, bv1.y, bv1.z, bv1.w};
            #pragma unroll
            for (int i = 0; i < 8; ++i)
                #pragma unroll
                for (int j = 0; j < 8; ++j)
                    acc[i][j] = fmaf(a[i], b[j], acc[i][j]);
        }
    }

    float fi[8], fb[8];
    #pragma unroll
    for (int i = 0; i < 8; ++i) fi[i] = invf[brow + ty * 8 + i];
    #pragma unroll
    for (int j = 0; j < 8; ++j) fb[j] = invb[bcol + tx * 8 + j];
    #pragma unroll
    for (int i = 0; i < 8; ++i) {
        size_t ro = (size_t)(brow + ty * 8 + i) * NB + bcol + tx * 8;
        #pragma unroll
        for (int j = 0; j < 8; ++j)
            dist[ro + j] = 1.0f - acc[i][j] * fi[i] * fb[j];
    }
}

// ---------------- top-8 per row (descending, ties -> lower index) -------------
__global__ __launch_bounds__(256) void topk_kernel(
    const float* __restrict__ dist, int* __restrict__ idxs)
{
    __shared__ float v[NB];
    __shared__ float rv[256];
    __shared__ int   ri[256];
    int row = blockIdx.x;
    const float* src = dist + (size_t)row * NB;
    for (int c = threadIdx.x; c < NB; c += 256) v[c] = src[c];
    __syncthreads();

    for (int sel = 0; sel < KSEL; ++sel) {
        float bv = -1e30f; int bi = NB;
        for (int c = threadIdx.x; c < NB; c += 256) {
            float x = v[c];
            if (x > bv) { bv = x; bi = c; }   // within thread, c increasing: first max kept
        }
        rv[threadIdx.x] = bv; ri[threadIdx.x] = bi;
        __syncthreads();
        for (int s = 128; s; s >>= 1) {
            if (threadIdx.x < s) {
                float ov = rv[threadIdx.x + s]; int oi = ri[threadIdx.x + s];
                if (ov > rv[threadIdx.x] ||
                    (ov == rv[threadIdx.x] && oi < ri[threadIdx.x])) {
                    rv[threadIdx.x] = ov; ri[threadIdx.x] = oi;
                }
            }
            __syncthreads();
        }
        if (threadIdx.x == 0) { idxs[row * KSEL + sel] = ri[0]; v[ri[0]] = -1e30f; }
        __syncthreads();
    }
}

// ---------------- pred_probs (mean of 8 gathered rows) + argmax label ---------
__global__ __launch_bounds__(256) void probs_kernel(
    const float* __restrict__ bank_probs, const int* __restrict__ idxs,
    float* __restrict__ out_labels, float* __restrict__ out_probs)
{
    int row = blockIdx.x;
    __shared__ int id[KSEL];
    if (threadIdx.x < KSEL) id[threadIdx.x] = idxs[row * KSEL + threadIdx.x];
    __syncthreads();

    float bv = -1e30f; int bc = NC;
    for (int c = threadIdx.x; c < NC; c += 256) {
        float s = 0.f;
        #pragma unroll
        for (int k = 0; k < KSEL; ++k) s += bank_probs[(size_t)id[k] * NC + c];
        s *= (1.0f / KSEL);
        out_probs[(size_t)row * NC + c] = s;
        if (s > bv) { bv = s; bc = c; }   // c increasing within thread
    }
    __shared__ float rv[256];
    __shared__ int   ri[256];
    rv[threadIdx.x] = bv; ri[threadIdx.x] = bc;
    __syncthreads();
    for (int s = 128; s; s >>= 1) {
        if (threadIdx.x < s) {
            float ov = rv[threadIdx.x + s]; int oi = ri[threadIdx.x + s];
            if (ov > rv[threadIdx.x] ||
                (ov == rv[threadIdx.x] && oi < ri[threadIdx.x])) {
                rv[threadIdx.x] = ov; ri[threadIdx.x] = oi;
            }
        }
        __syncthreads();
    }
    if (threadIdx.x == 0) out_labels[row] = (float)ri[0];
}

// ---------------- grads: mean of 8 gathered bank_features rows ----------------
__global__ __launch_bounds__(256) void grads_kernel(
    const float* __restrict__ bank, const int* __restrict__ idxs,
    float* __restrict__ out_grads)
{
    int row = blockIdx.x;
    __shared__ int id[KSEL];
    if (threadIdx.x < KSEL) id[threadIdx.x] = idxs[row * KSEL + threadIdx.x];
    __syncthreads();
    for (int c = threadIdx.x; c < DIM / 4; c += 256) {
        float4 acc = {0.f, 0.f, 0.f, 0.f};
        #pragma unroll
        for (int k = 0; k < KSEL; ++k) {
            float4 t = ((const float4*)(bank + (size_t)id[k] * DIM))[c];
            acc.x += t.x; acc.y += t.y; acc.z += t.z; acc.w += t.w;
        }
        float4 o = {acc.x * 0.125f, acc.y * 0.125f, acc.z * 0.125f, acc.w * 0.125f};
        ((float4*)(out_grads + (size_t)row * DIM))[c] = o;
    }
}

// ---------------- pred_images: mean of 8 gathered images ----------------------
__global__ __launch_bounds__(256) void images_kernel(
    const float* __restrict__ image_bank, const int* __restrict__ idxs,
    float* __restrict__ out_images)
{
    int row = blockIdx.y;
    int off = blockIdx.x * 256 + threadIdx.x;   // float4 index, IMG/4 = 37632
    __shared__ int id[KSEL];
    if (threadIdx.x < KSEL) id[threadIdx.x] = idxs[row * KSEL + threadIdx.x];
    __syncthreads();

    float4 acc = ((const float4*)(image_bank + (size_t)id[0] * IMG))[off];
    #pragma unroll
    for (int k = 1; k < KSEL; ++k) {
        float4 t = ((const float4*)(image_bank + (size_t)id[k] * IMG))[off];
        acc.x += t.x; acc.y += t.y; acc.z += t.z; acc.w += t.w;
    }
    float4 o = {acc.x * 0.125f, acc.y * 0.125f, acc.z * 0.125f, acc.w * 0.125f};
    ((float4*)(out_images + (size_t)row * IMG))[off] = o;
}

extern "C" void kernel_launch(void* const* d_in, const int* in_sizes, int n_in,
                              void* d_out, int out_size, void* d_ws, size_t ws_size,
                              hipStream_t stream)
{
    const float* feats      = (const float*)d_in[0];
    const float* bank_feats = (const float*)d_in[1];
    const float* bank_probs = (const float*)d_in[2];
    const float* image_bank = (const float*)d_in[3];

    float* out = (float*)d_out;
    // output layout: labels[1024] | probs[1024*1000] | images[1024*150528] | grads[1024*2048]
    float* out_labels = out;
    float* out_probs  = out + NF;
    float* out_images = out + NF + (size_t)NF * NC;
    float* out_grads  = out + NF + (size_t)NF * NC + (size_t)NF * IMG;

    // dist matrix scratch lives inside the pred_images output region (it is
    // fully overwritten by images_kernel, which runs last) — deterministic.
    float* dist = out_images;

    // small scratch in d_ws: invf[NF] | invb[NB] | idxs[NF*KSEL] (~45 KB)
    float* invf = (float*)d_ws;
    float* invb = invf + NF;
    int*   idxs = (int*)(invb + NB);

    norms_kernel<<<NF + NB, 256, 0, stream>>>(feats, bank_feats, invf, invb);

    dim3 ggrid(NB / GBN, NF / GBM);   // (16, 8)
    dist_kernel<<<ggrid, 256, 0, stream>>>(feats, bank_feats, invf, invb, dist);

    topk_kernel<<<NF, 256, 0, stream>>>(dist, idxs);

    probs_kernel<<<NF, 256, 0, stream>>>(bank_probs, idxs, out_labels, out_probs);

    grads_kernel<<<NF, 256, 0, stream>>>(bank_feats, idxs, out_grads);

    // runs last: overwrites the dist scratch with the real pred_images
    dim3 igrid(IMG / 4 / 256, NF);    // (147, 1024)
    images_kernel<<<igrid, 256, 0, stream>>>(image_bank, idxs, out_images);
}

// Round 3
// 994.109 us; speedup vs baseline: 1.2389x; 1.2389x over previous
//
#include <hip/hip_runtime.h>
#include <math.h>

#define NF   1024
#define NB   2048
#define DIM  2048
#define NC   1000
#define IMG  150528   // 3*224*224, = 37632 float4
#define IMG4 37632
#define KSEL 8

typedef float f32x4 __attribute__((ext_vector_type(4)));

// ---------------- norms: 1/max(||row||,eps) for feats and bank ----------------
__global__ __launch_bounds__(256) void norms_kernel(
    const float* __restrict__ feats, const float* __restrict__ bank,
    float* __restrict__ invf, float* __restrict__ invb)
{
    int row = blockIdx.x;
    const float* src;
    float* dst;
    if (row < NF) { src = feats + (size_t)row * DIM; dst = invf + row; }
    else          { src = bank  + (size_t)(row - NF) * DIM; dst = invb + (row - NF); }

    float s = 0.f;
    for (int c = threadIdx.x; c < DIM / 4; c += 256) {
        float4 v = ((const float4*)src)[c];
        s += v.x * v.x + v.y * v.y + v.z * v.z + v.w * v.w;
    }
    __shared__ float red[4];
    for (int off = 32; off; off >>= 1) s += __shfl_down(s, off, 64);
    if ((threadIdx.x & 63) == 0) red[threadIdx.x >> 6] = s;
    __syncthreads();
    if (threadIdx.x == 0) {
        float t = red[0] + red[1] + red[2] + red[3];
        float n = fmaxf(sqrtf(t), 1e-12f);
        *dst = 1.0f / n;
    }
}

// ------ dist GEMM: dist[i][j] = 1 - (A_i . B_j) * invf[i] * invb[j] ----------
// 128x64 tile -> grid (32,8) = 256 workgroups (one per CU).
#define GBM 128
#define GBN 64
#define GBK 16

__global__ __launch_bounds__(256) void dist_kernel(
    const float* __restrict__ A, const float* __restrict__ B,
    const float* __restrict__ invf, const float* __restrict__ invb,
    float* __restrict__ dist)
{
    __shared__ float As[GBK][GBM];   // k-major
    __shared__ float Bs[GBK][GBN];

    const int tid  = threadIdx.x;
    const int brow = blockIdx.y * GBM;   // over NF
    const int bcol = blockIdx.x * GBN;   // over NB
    const int ty   = tid >> 4;           // 0..15 -> rows ty*8..+7
    const int tx   = tid & 15;           // 0..15 -> cols tx*4..+3

    const int lrow = tid >> 2;           // 0..63
    const int lk   = (tid & 3) * 4;      // 0,4,8,12

    float acc[8][4] = {};

    for (int k0 = 0; k0 < DIM; k0 += GBK) {
        float4 a0 = *(const float4*)(A + (size_t)(brow + lrow)      * DIM + k0 + lk);
        float4 a1 = *(const float4*)(A + (size_t)(brow + lrow + 64) * DIM + k0 + lk);
        float4 b0 = *(const float4*)(B + (size_t)(bcol + lrow)      * DIM + k0 + lk);
        __syncthreads();   // previous iteration's LDS reads done
        As[lk + 0][lrow] = a0.x; As[lk + 1][lrow] = a0.y;
        As[lk + 2][lrow] = a0.z; As[lk + 3][lrow] = a0.w;
        As[lk + 0][lrow + 64] = a1.x; As[lk + 1][lrow + 64] = a1.y;
        As[lk + 2][lrow + 64] = a1.z; As[lk + 3][lrow + 64] = a1.w;
        Bs[lk + 0][lrow] = b0.x; Bs[lk + 1][lrow] = b0.y;
        Bs[lk + 2][lrow] = b0.z; Bs[lk + 3][lrow] = b0.w;
        __syncthreads();

        #pragma unroll
        for (int k = 0; k < GBK; ++k) {
            float4 av0 = *(const float4*)&As[k][ty * 8];
            float4 av1 = *(const float4*)&As[k][ty * 8 + 4];
            float4 bv0 = *(const float4*)&Bs[k][tx * 4];
            float a[8] = {av0.x, av0.y, av0.z, av0.w, av1.x, av1.y, av1.z, av1.w};
            float b[4] = {bv0.x, bv0.y, bv0.z, bv0.w};
            #pragma unroll
            for (int i = 0; i < 8; ++i)
                #pragma unroll
                for (int j = 0; j < 4; ++j)
                    acc[i][j] = fmaf(a[i], b[j], acc[i][j]);
        }
    }

    float fi[8], fb[4];
    #pragma unroll
    for (int i = 0; i < 8; ++i) fi[i] = invf[brow + ty * 8 + i];
    #pragma unroll
    for (int j = 0; j < 4; ++j) fb[j] = invb[bcol + tx * 4 + j];
    #pragma unroll
    for (int i = 0; i < 8; ++i) {
        size_t ro = (size_t)(brow + ty * 8 + i) * NB + bcol + tx * 4;
        float4 o;
        o.x = 1.0f - acc[i][0] * fi[i] * fb[0];
        o.y = 1.0f - acc[i][1] * fi[i] * fb[1];
        o.z = 1.0f - acc[i][2] * fi[i] * fb[2];
        o.w = 1.0f - acc[i][3] * fi[i] * fb[3];
        *(float4*)(dist + ro) = o;
    }
}

// ---------------- top-8 per row (descending, ties -> lower index) -------------
__global__ __launch_bounds__(256) void topk_kernel(
    const float* __restrict__ dist, int* __restrict__ idxs)
{
    __shared__ float v[NB];
    __shared__ float rv[256];
    __shared__ int   ri[256];
    int row = blockIdx.x;
    const float* src = dist + (size_t)row * NB;
    for (int c = threadIdx.x; c < NB; c += 256) v[c] = src[c];
    __syncthreads();

    for (int sel = 0; sel < KSEL; ++sel) {
        float bv = -1e30f; int bi = NB;
        for (int c = threadIdx.x; c < NB; c += 256) {
            float x = v[c];
            if (x > bv) { bv = x; bi = c; }   // c increasing: first max kept
        }
        rv[threadIdx.x] = bv; ri[threadIdx.x] = bi;
        __syncthreads();
        for (int s = 128; s; s >>= 1) {
            if (threadIdx.x < s) {
                float ov = rv[threadIdx.x + s]; int oi = ri[threadIdx.x + s];
                if (ov > rv[threadIdx.x] ||
                    (ov == rv[threadIdx.x] && oi < ri[threadIdx.x])) {
                    rv[threadIdx.x] = ov; ri[threadIdx.x] = oi;
                }
            }
            __syncthreads();
        }
        if (threadIdx.x == 0) { idxs[row * KSEL + sel] = ri[0]; v[ri[0]] = -1e30f; }
        __syncthreads();
    }
}

// ---------------- pred_probs (mean of 8 gathered rows) + argmax label ---------
__global__ __launch_bounds__(256) void probs_kernel(
    const float* __restrict__ bank_probs, const int* __restrict__ idxs,
    float* __restrict__ out_labels, float* __restrict__ out_probs)
{
    int row = blockIdx.x;
    __shared__ int id[KSEL];
    if (threadIdx.x < KSEL) id[threadIdx.x] = idxs[row * KSEL + threadIdx.x];
    __syncthreads();

    float bv = -1e30f; int bc = NC;
    for (int c = threadIdx.x; c < NC; c += 256) {
        float s = 0.f;
        #pragma unroll
        for (int k = 0; k < KSEL; ++k) s += bank_probs[(size_t)id[k] * NC + c];
        s *= (1.0f / KSEL);
        out_probs[(size_t)row * NC + c] = s;
        if (s > bv) { bv = s; bc = c; }
    }
    __shared__ float rv[256];
    __shared__ int   ri[256];
    rv[threadIdx.x] = bv; ri[threadIdx.x] = bc;
    __syncthreads();
    for (int s = 128; s; s >>= 1) {
        if (threadIdx.x < s) {
            float ov = rv[threadIdx.x + s]; int oi = ri[threadIdx.x + s];
            if (ov > rv[threadIdx.x] ||
                (ov == rv[threadIdx.x] && oi < ri[threadIdx.x])) {
                rv[threadIdx.x] = ov; ri[threadIdx.x] = oi;
            }
        }
        __syncthreads();
    }
    if (threadIdx.x == 0) out_labels[row] = (float)ri[0];
}

// ---------------- grads: mean of 8 gathered bank_features rows ----------------
__global__ __launch_bounds__(256) void grads_kernel(
    const float* __restrict__ bank, const int* __restrict__ idxs,
    float* __restrict__ out_grads)
{
    int row = blockIdx.x;
    __shared__ int id[KSEL];
    if (threadIdx.x < KSEL) id[threadIdx.x] = idxs[row * KSEL + threadIdx.x];
    __syncthreads();
    for (int c = threadIdx.x; c < DIM / 4; c += 256) {
        float4 acc = {0.f, 0.f, 0.f, 0.f};
        #pragma unroll
        for (int k = 0; k < KSEL; ++k) {
            float4 t = ((const float4*)(bank + (size_t)id[k] * DIM))[c];
            acc.x += t.x; acc.y += t.y; acc.z += t.z; acc.w += t.w;
        }
        float4 o = {acc.x * 0.125f, acc.y * 0.125f, acc.z * 0.125f, acc.w * 0.125f};
        ((float4*)(out_grads + (size_t)row * DIM))[c] = o;
    }
}

// ---------------- pred_images: mean of 8 gathered images ----------------------
// L3-tiled: 7 column-tiles; per tile each image contributes 21504 floats
// (84 KB) -> resident-tile footprint 2048*84KB = 172 MB < 256 MB L3.
// Tile index is the SLOWEST grid dimension so the device sweeps one tile's
// worth of the bank at a time; re-referenced images hit Infinity Cache.
// Output stores are non-temporal so 0.6 GB of streaming writes don't evict
// the resident tile.
#define ITILES 7
#define CBS    7            // col-blocks per tile; 7*7=49 col-blocks total
#define V4PT   3            // float4 per thread; block covers 3*256=768 float4
// 49 col-blocks * 768 float4 = 37632 = IMG4  ✓

__global__ __launch_bounds__(256) void images_kernel(
    const float* __restrict__ image_bank, const int* __restrict__ idxs,
    float* __restrict__ out_images)
{
    const int bid  = blockIdx.x;
    const int tile = bid / (CBS * NF);
    const int rem  = bid % (CBS * NF);
    const int row  = rem / CBS;
    const int cb   = rem % CBS;
    const int base4 = (tile * CBS + cb) * (V4PT * 256) + threadIdx.x;

    __shared__ int id[KSEL];
    if (threadIdx.x < KSEL) id[threadIdx.x] = idxs[row * KSEL + threadIdx.x];
    __syncthreads();

    const f32x4* bank4 = (const f32x4*)image_bank;
    f32x4* out4 = (f32x4*)(out_images + (size_t)row * IMG);

    #pragma unroll
    for (int v = 0; v < V4PT; ++v) {
        const int f4 = base4 + v * 256;
        f32x4 t[KSEL];
        #pragma unroll
        for (int k = 0; k < KSEL; ++k)
            t[k] = bank4[(size_t)id[k] * IMG4 + f4];
        // pairwise tree to shorten the dependency chain
        f32x4 s01 = t[0] + t[1];
        f32x4 s23 = t[2] + t[3];
        f32x4 s45 = t[4] + t[5];
        f32x4 s67 = t[6] + t[7];
        f32x4 o = ((s01 + s23) + (s45 + s67)) * 0.125f;
        __builtin_nontemporal_store(o, out4 + f4);
    }
}

extern "C" void kernel_launch(void* const* d_in, const int* in_sizes, int n_in,
                              void* d_out, int out_size, void* d_ws, size_t ws_size,
                              hipStream_t stream)
{
    const float* feats      = (const float*)d_in[0];
    const float* bank_feats = (const float*)d_in[1];
    const float* bank_probs = (const float*)d_in[2];
    const float* image_bank = (const float*)d_in[3];

    float* out = (float*)d_out;
    // output layout: labels[1024] | probs[1024*1000] | images[1024*150528] | grads[1024*2048]
    float* out_labels = out;
    float* out_probs  = out + NF;
    float* out_images = out + NF + (size_t)NF * NC;
    float* out_grads  = out + NF + (size_t)NF * NC + (size_t)NF * IMG;

    // dist matrix scratch lives inside the pred_images output region (it is
    // fully overwritten by images_kernel, which runs last) — deterministic.
    float* dist = out_images;

    // small scratch in d_ws: invf[NF] | invb[NB] | idxs[NF*KSEL] (~45 KB)
    float* invf = (float*)d_ws;
    float* invb = invf + NF;
    int*   idxs = (int*)(invb + NB);

    norms_kernel<<<NF + NB, 256, 0, stream>>>(feats, bank_feats, invf, invb);

    dim3 ggrid(NB / GBN, NF / GBM);   // (32, 8) = 256 workgroups
    dist_kernel<<<ggrid, 256, 0, stream>>>(feats, bank_feats, invf, invb, dist);

    topk_kernel<<<NF, 256, 0, stream>>>(dist, idxs);

    probs_kernel<<<NF, 256, 0, stream>>>(bank_probs, idxs, out_labels, out_probs);

    grads_kernel<<<NF, 256, 0, stream>>>(bank_feats, idxs, out_grads);

    // runs last: overwrites the dist scratch with the real pred_images
    images_kernel<<<ITILES * CBS * NF, 256, 0, stream>>>(image_bank, idxs, out_images);
}

// Round 4
// 991.263 us; speedup vs baseline: 1.2425x; 1.0029x over previous
//
#include <hip/hip_runtime.h>
#include <math.h>

#define NF   1024
#define NB   2048
#define DIM  2048
#define NC   1000
#define IMG  150528   // 3*224*224, = 37632 float4
#define IMG4 37632
#define KSEL 8

typedef float f32x4 __attribute__((ext_vector_type(4)));

// ---------------- norms: 1/max(||row||,eps) for feats and bank ----------------
__global__ __launch_bounds__(256) void norms_kernel(
    const float* __restrict__ feats, const float* __restrict__ bank,
    float* __restrict__ invf, float* __restrict__ invb)
{
    int row = blockIdx.x;
    const float* src;
    float* dst;
    if (row < NF) { src = feats + (size_t)row * DIM; dst = invf + row; }
    else          { src = bank  + (size_t)(row - NF) * DIM; dst = invb + (row - NF); }

    float s = 0.f;
    for (int c = threadIdx.x; c < DIM / 4; c += 256) {
        float4 v = ((const float4*)src)[c];
        s += v.x * v.x + v.y * v.y + v.z * v.z + v.w * v.w;
    }
    __shared__ float red[4];
    for (int off = 32; off; off >>= 1) s += __shfl_down(s, off, 64);
    if ((threadIdx.x & 63) == 0) red[threadIdx.x >> 6] = s;
    __syncthreads();
    if (threadIdx.x == 0) {
        float t = red[0] + red[1] + red[2] + red[3];
        float n = fmaxf(sqrtf(t), 1e-12f);
        *dst = 1.0f / n;
    }
}

// ------ dist GEMM: dist[i][j] = 1 - (A_i . B_j) * invf[i] * invb[j] ----------
// 128x64 tile -> grid (32,8) = 256 workgroups (one per CU).
#define GBM 128
#define GBN 64
#define GBK 16

__global__ __launch_bounds__(256) void dist_kernel(
    const float* __restrict__ A, const float* __restrict__ B,
    const float* __restrict__ invf, const float* __restrict__ invb,
    float* __restrict__ dist)
{
    __shared__ float As[GBK][GBM];   // k-major
    __shared__ float Bs[GBK][GBN];

    const int tid  = threadIdx.x;
    const int brow = blockIdx.y * GBM;   // over NF
    const int bcol = blockIdx.x * GBN;   // over NB
    const int ty   = tid >> 4;           // 0..15 -> rows ty*8..+7
    const int tx   = tid & 15;           // 0..15 -> cols tx*4..+3

    const int lrow = tid >> 2;           // 0..63
    const int lk   = (tid & 3) * 4;      // 0,4,8,12

    float acc[8][4] = {};

    for (int k0 = 0; k0 < DIM; k0 += GBK) {
        float4 a0 = *(const float4*)(A + (size_t)(brow + lrow)      * DIM + k0 + lk);
        float4 a1 = *(const float4*)(A + (size_t)(brow + lrow + 64) * DIM + k0 + lk);
        float4 b0 = *(const float4*)(B + (size_t)(bcol + lrow)      * DIM + k0 + lk);
        __syncthreads();   // previous iteration's LDS reads done
        As[lk + 0][lrow] = a0.x; As[lk + 1][lrow] = a0.y;
        As[lk + 2][lrow] = a0.z; As[lk + 3][lrow] = a0.w;
        As[lk + 0][lrow + 64] = a1.x; As[lk + 1][lrow + 64] = a1.y;
        As[lk + 2][lrow + 64] = a1.z; As[lk + 3][lrow + 64] = a1.w;
        Bs[lk + 0][lrow] = b0.x; Bs[lk + 1][lrow] = b0.y;
        Bs[lk + 2][lrow] = b0.z; Bs[lk + 3][lrow] = b0.w;
        __syncthreads();

        #pragma unroll
        for (int k = 0; k < GBK; ++k) {
            float4 av0 = *(const float4*)&As[k][ty * 8];
            float4 av1 = *(const float4*)&As[k][ty * 8 + 4];
            float4 bv0 = *(const float4*)&Bs[k][tx * 4];
            float a[8] = {av0.x, av0.y, av0.z, av0.w, av1.x, av1.y, av1.z, av1.w};
            float b[4] = {bv0.x, bv0.y, bv0.z, bv0.w};
            #pragma unroll
            for (int i = 0; i < 8; ++i)
                #pragma unroll
                for (int j = 0; j < 4; ++j)
                    acc[i][j] = fmaf(a[i], b[j], acc[i][j]);
        }
    }

    float fi[8], fb[4];
    #pragma unroll
    for (int i = 0; i < 8; ++i) fi[i] = invf[brow + ty * 8 + i];
    #pragma unroll
    for (int j = 0; j < 4; ++j) fb[j] = invb[bcol + tx * 4 + j];
    #pragma unroll
    for (int i = 0; i < 8; ++i) {
        size_t ro = (size_t)(brow + ty * 8 + i) * NB + bcol + tx * 4;
        float4 o;
        o.x = 1.0f - acc[i][0] * fi[i] * fb[0];
        o.y = 1.0f - acc[i][1] * fi[i] * fb[1];
        o.z = 1.0f - acc[i][2] * fi[i] * fb[2];
        o.w = 1.0f - acc[i][3] * fi[i] * fb[3];
        *(float4*)(dist + ro) = o;
    }
}

// ---------------- top-8 per row (descending, ties -> lower index) -------------
__global__ __launch_bounds__(256) void topk_kernel(
    const float* __restrict__ dist, int* __restrict__ idxs)
{
    __shared__ float v[NB];
    __shared__ float rv[256];
    __shared__ int   ri[256];
    int row = blockIdx.x;
    const float* src = dist + (size_t)row * NB;
    for (int c = threadIdx.x; c < NB; c += 256) v[c] = src[c];
    __syncthreads();

    for (int sel = 0; sel < KSEL; ++sel) {
        float bv = -1e30f; int bi = NB;
        for (int c = threadIdx.x; c < NB; c += 256) {
            float x = v[c];
            if (x > bv) { bv = x; bi = c; }   // c increasing: first max kept
        }
        rv[threadIdx.x] = bv; ri[threadIdx.x] = bi;
        __syncthreads();
        for (int s = 128; s; s >>= 1) {
            if (threadIdx.x < s) {
                float ov = rv[threadIdx.x + s]; int oi = ri[threadIdx.x + s];
                if (ov > rv[threadIdx.x] ||
                    (ov == rv[threadIdx.x] && oi < ri[threadIdx.x])) {
                    rv[threadIdx.x] = ov; ri[threadIdx.x] = oi;
                }
            }
            __syncthreads();
        }
        if (threadIdx.x == 0) { idxs[row * KSEL + sel] = ri[0]; v[ri[0]] = -1e30f; }
        __syncthreads();
    }
}

// ---------------- pred_probs (mean of 8 gathered rows) + argmax label ---------
__global__ __launch_bounds__(256) void probs_kernel(
    const float* __restrict__ bank_probs, const int* __restrict__ idxs,
    float* __restrict__ out_labels, float* __restrict__ out_probs)
{
    int row = blockIdx.x;
    __shared__ int id[KSEL];
    if (threadIdx.x < KSEL) id[threadIdx.x] = idxs[row * KSEL + threadIdx.x];
    __syncthreads();

    float bv = -1e30f; int bc = NC;
    for (int c = threadIdx.x; c < NC; c += 256) {
        float s = 0.f;
        #pragma unroll
        for (int k = 0; k < KSEL; ++k) s += bank_probs[(size_t)id[k] * NC + c];
        s *= (1.0f / KSEL);
        out_probs[(size_t)row * NC + c] = s;
        if (s > bv) { bv = s; bc = c; }
    }
    __shared__ float rv[256];
    __shared__ int   ri[256];
    rv[threadIdx.x] = bv; ri[threadIdx.x] = bc;
    __syncthreads();
    for (int s = 128; s; s >>= 1) {
        if (threadIdx.x < s) {
            float ov = rv[threadIdx.x + s]; int oi = ri[threadIdx.x + s];
            if (ov > rv[threadIdx.x] ||
                (ov == rv[threadIdx.x] && oi < ri[threadIdx.x])) {
                rv[threadIdx.x] = ov; ri[threadIdx.x] = oi;
            }
        }
        __syncthreads();
    }
    if (threadIdx.x == 0) out_labels[row] = (float)ri[0];
}

// ---------------- grads: mean of 8 gathered bank_features rows ----------------
__global__ __launch_bounds__(256) void grads_kernel(
    const float* __restrict__ bank, const int* __restrict__ idxs,
    float* __restrict__ out_grads)
{
    int row = blockIdx.x;
    __shared__ int id[KSEL];
    if (threadIdx.x < KSEL) id[threadIdx.x] = idxs[row * KSEL + threadIdx.x];
    __syncthreads();
    for (int c = threadIdx.x; c < DIM / 4; c += 256) {
        float4 acc = {0.f, 0.f, 0.f, 0.f};
        #pragma unroll
        for (int k = 0; k < KSEL; ++k) {
            float4 t = ((const float4*)(bank + (size_t)id[k] * DIM))[c];
            acc.x += t.x; acc.y += t.y; acc.z += t.z; acc.w += t.w;
        }
        float4 o = {acc.x * 0.125f, acc.y * 0.125f, acc.z * 0.125f, acc.w * 0.125f};
        ((float4*)(out_grads + (size_t)row * DIM))[c] = o;
    }
}

// ---------------- pred_images: mean of 8 gathered images ----------------------
// L3-tiled (7 column-tiles, tile = slowest grid dim) so bank re-references hit
// Infinity Cache. Non-temporal output stores keep 0.6 GB of streaming writes
// from evicting the resident tile.
// MLP: all 24 gather loads (3 float4-iters x 8 images) are issued before any
// reduction; loads are v-major so the v-th reduce waits at vmcnt(16)/(8)/(0),
// keeping 16 loads in flight through each reduce+store.
#define ITILES 7
#define CBS    7            // col-blocks per tile; 7*7=49 col-blocks total
#define V4PT   3            // float4 per thread; block covers 3*256=768 float4
// 49 col-blocks * 768 float4 = 37632 = IMG4  ✓

__global__ __launch_bounds__(256) void images_kernel(
    const float* __restrict__ image_bank, const int* __restrict__ idxs,
    float* __restrict__ out_images)
{
    const int bid  = blockIdx.x;
    const int tile = bid / (CBS * NF);
    const int rem  = bid % (CBS * NF);
    const int row  = rem / CBS;
    const int cb   = rem % CBS;
    const int base4 = (tile * CBS + cb) * (V4PT * 256) + threadIdx.x;

    __shared__ int id[KSEL];
    if (threadIdx.x < KSEL) id[threadIdx.x] = idxs[row * KSEL + threadIdx.x];
    __syncthreads();

    const f32x4* __restrict__ bank4 = (const f32x4*)image_bank;
    f32x4* out4 = (f32x4*)(out_images + (size_t)row * IMG) + base4;

    const f32x4* p[KSEL];
    #pragma unroll
    for (int k = 0; k < KSEL; ++k)
        p[k] = bank4 + (size_t)id[k] * IMG4 + base4;

    f32x4 t[V4PT][KSEL];
    #pragma unroll
    for (int v = 0; v < V4PT; ++v)
        #pragma unroll
        for (int k = 0; k < KSEL; ++k)
            t[v][k] = p[k][v * 256];

    #pragma unroll
    for (int v = 0; v < V4PT; ++v) {
        f32x4 s01 = t[v][0] + t[v][1];
        f32x4 s23 = t[v][2] + t[v][3];
        f32x4 s45 = t[v][4] + t[v][5];
        f32x4 s67 = t[v][6] + t[v][7];
        f32x4 o = ((s01 + s23) + (s45 + s67)) * 0.125f;
        __builtin_nontemporal_store(o, out4 + v * 256);
    }
}

extern "C" void kernel_launch(void* const* d_in, const int* in_sizes, int n_in,
                              void* d_out, int out_size, void* d_ws, size_t ws_size,
                              hipStream_t stream)
{
    const float* feats      = (const float*)d_in[0];
    const float* bank_feats = (const float*)d_in[1];
    const float* bank_probs = (const float*)d_in[2];
    const float* image_bank = (const float*)d_in[3];

    float* out = (float*)d_out;
    // output layout: labels[1024] | probs[1024*1000] | images[1024*150528] | grads[1024*2048]
    float* out_labels = out;
    float* out_probs  = out + NF;
    float* out_images = out + NF + (size_t)NF * NC;
    float* out_grads  = out + NF + (size_t)NF * NC + (size_t)NF * IMG;

    // dist matrix scratch lives inside the pred_images output region (it is
    // fully overwritten by images_kernel, which runs last) — deterministic.
    float* dist = out_images;

    // small scratch in d_ws: invf[NF] | invb[NB] | idxs[NF*KSEL] (~45 KB)
    float* invf = (float*)d_ws;
    float* invb = invf + NF;
    int*   idxs = (int*)(invb + NB);

    norms_kernel<<<NF + NB, 256, 0, stream>>>(feats, bank_feats, invf, invb);

    dim3 ggrid(NB / GBN, NF / GBM);   // (32, 8) = 256 workgroups
    dist_kernel<<<ggrid, 256, 0, stream>>>(feats, bank_feats, invf, invb, dist);

    topk_kernel<<<NF, 256, 0, stream>>>(dist, idxs);

    probs_kernel<<<NF, 256, 0, stream>>>(bank_probs, idxs, out_labels, out_probs);

    grads_kernel<<<NF, 256, 0, stream>>>(bank_feats, idxs, out_grads);

    // runs last: overwrites the dist scratch with the real pred_images
    images_kernel<<<ITILES * CBS * NF, 256, 0, stream>>>(image_bank, idxs, out_images);
}

// Round 5
// 915.179 us; speedup vs baseline: 1.3458x; 1.0831x over previous
//
#include <hip/hip_runtime.h>
#include <math.h>

#define NF   1024
#define NB   2048
#define DIM  2048
#define NC   1000
#define IMG  150528   // 3*224*224, = 37632 float4
#define IMG4 37632
#define KSEL 8

typedef float f32x4 __attribute__((ext_vector_type(4)));

// ---------------- norms: 1/max(||row||,eps) for feats and bank ----------------
__global__ __launch_bounds__(256) void norms_kernel(
    const float* __restrict__ feats, const float* __restrict__ bank,
    float* __restrict__ invf, float* __restrict__ invb)
{
    int row = blockIdx.x;
    const float* src;
    float* dst;
    if (row < NF) { src = feats + (size_t)row * DIM; dst = invf + row; }
    else          { src = bank  + (size_t)(row - NF) * DIM; dst = invb + (row - NF); }

    float s = 0.f;
    for (int c = threadIdx.x; c < DIM / 4; c += 256) {
        float4 v = ((const float4*)src)[c];
        s += v.x * v.x + v.y * v.y + v.z * v.z + v.w * v.w;
    }
    __shared__ float red[4];
    for (int off = 32; off; off >>= 1) s += __shfl_down(s, off, 64);
    if ((threadIdx.x & 63) == 0) red[threadIdx.x >> 6] = s;
    __syncthreads();
    if (threadIdx.x == 0) {
        float t = red[0] + red[1] + red[2] + red[3];
        float n = fmaxf(sqrtf(t), 1e-12f);
        *dst = 1.0f / n;
    }
}

// ------ dist GEMM: dist[i][j] = 1 - (A_i . B_j) * invf[i] * invb[j] ----------
// 128x64 tile -> grid (32,8) = 256 workgroups (one per CU).
#define GBM 128
#define GBN 64
#define GBK 16

__global__ __launch_bounds__(256) void dist_kernel(
    const float* __restrict__ A, const float* __restrict__ B,
    const float* __restrict__ invf, const float* __restrict__ invb,
    float* __restrict__ dist)
{
    __shared__ float As[GBK][GBM];   // k-major
    __shared__ float Bs[GBK][GBN];

    const int tid  = threadIdx.x;
    const int brow = blockIdx.y * GBM;   // over NF
    const int bcol = blockIdx.x * GBN;   // over NB
    const int ty   = tid >> 4;           // 0..15 -> rows ty*8..+7
    const int tx   = tid & 15;           // 0..15 -> cols tx*4..+3

    const int lrow = tid >> 2;           // 0..63
    const int lk   = (tid & 3) * 4;      // 0,4,8,12

    float acc[8][4] = {};

    for (int k0 = 0; k0 < DIM; k0 += GBK) {
        float4 a0 = *(const float4*)(A + (size_t)(brow + lrow)      * DIM + k0 + lk);
        float4 a1 = *(const float4*)(A + (size_t)(brow + lrow + 64) * DIM + k0 + lk);
        float4 b0 = *(const float4*)(B + (size_t)(bcol + lrow)      * DIM + k0 + lk);
        __syncthreads();   // previous iteration's LDS reads done
        As[lk + 0][lrow] = a0.x; As[lk + 1][lrow] = a0.y;
        As[lk + 2][lrow] = a0.z; As[lk + 3][lrow] = a0.w;
        As[lk + 0][lrow + 64] = a1.x; As[lk + 1][lrow + 64] = a1.y;
        As[lk + 2][lrow + 64] = a1.z; As[lk + 3][lrow + 64] = a1.w;
        Bs[lk + 0][lrow] = b0.x; Bs[lk + 1][lrow] = b0.y;
        Bs[lk + 2][lrow] = b0.z; Bs[lk + 3][lrow] = b0.w;
        __syncthreads();

        #pragma unroll
        for (int k = 0; k < GBK; ++k) {
            float4 av0 = *(const float4*)&As[k][ty * 8];
            float4 av1 = *(const float4*)&As[k][ty * 8 + 4];
            float4 bv0 = *(const float4*)&Bs[k][tx * 4];
            float a[8] = {av0.x, av0.y, av0.z, av0.w, av1.x, av1.y, av1.z, av1.w};
            float b[4] = {bv0.x, bv0.y, bv0.z, bv0.w};
            #pragma unroll
            for (int i = 0; i < 8; ++i)
                #pragma unroll
                for (int j = 0; j < 4; ++j)
                    acc[i][j] = fmaf(a[i], b[j], acc[i][j]);
        }
    }

    float fi[8], fb[4];
    #pragma unroll
    for (int i = 0; i < 8; ++i) fi[i] = invf[brow + ty * 8 + i];
    #pragma unroll
    for (int j = 0; j < 4; ++j) fb[j] = invb[bcol + tx * 4 + j];
    #pragma unroll
    for (int i = 0; i < 8; ++i) {
        size_t ro = (size_t)(brow + ty * 8 + i) * NB + bcol + tx * 4;
        float4 o;
        o.x = 1.0f - acc[i][0] * fi[i] * fb[0];
        o.y = 1.0f - acc[i][1] * fi[i] * fb[1];
        o.z = 1.0f - acc[i][2] * fi[i] * fb[2];
        o.w = 1.0f - acc[i][3] * fi[i] * fb[3];
        *(float4*)(dist + ro) = o;
    }
}

// ---------------- top-8 per row (descending, ties -> lower index) -------------
__global__ __launch_bounds__(256) void topk_kernel(
    const float* __restrict__ dist, int* __restrict__ idxs)
{
    __shared__ float v[NB];
    __shared__ float rv[256];
    __shared__ int   ri[256];
    int row = blockIdx.x;
    const float* src = dist + (size_t)row * NB;
    for (int c = threadIdx.x; c < NB; c += 256) v[c] = src[c];
    __syncthreads();

    for (int sel = 0; sel < KSEL; ++sel) {
        float bv = -1e30f; int bi = NB;
        for (int c = threadIdx.x; c < NB; c += 256) {
            float x = v[c];
            if (x > bv) { bv = x; bi = c; }   // c increasing: first max kept
        }
        rv[threadIdx.x] = bv; ri[threadIdx.x] = bi;
        __syncthreads();
        for (int s = 128; s; s >>= 1) {
            if (threadIdx.x < s) {
                float ov = rv[threadIdx.x + s]; int oi = ri[threadIdx.x + s];
                if (ov > rv[threadIdx.x] ||
                    (ov == rv[threadIdx.x] && oi < ri[threadIdx.x])) {
                    rv[threadIdx.x] = ov; ri[threadIdx.x] = oi;
                }
            }
            __syncthreads();
        }
        if (threadIdx.x == 0) { idxs[row * KSEL + sel] = ri[0]; v[ri[0]] = -1e30f; }
        __syncthreads();
    }
}

// ---------------- pred_probs (mean of 8 gathered rows) + argmax label ---------
__global__ __launch_bounds__(256) void probs_kernel(
    const float* __restrict__ bank_probs, const int* __restrict__ idxs,
    float* __restrict__ out_labels, float* __restrict__ out_probs)
{
    int row = blockIdx.x;
    __shared__ int id[KSEL];
    if (threadIdx.x < KSEL) id[threadIdx.x] = idxs[row * KSEL + threadIdx.x];
    __syncthreads();

    float bv = -1e30f; int bc = NC;
    for (int c = threadIdx.x; c < NC; c += 256) {
        float s = 0.f;
        #pragma unroll
        for (int k = 0; k < KSEL; ++k) s += bank_probs[(size_t)id[k] * NC + c];
        s *= (1.0f / KSEL);
        out_probs[(size_t)row * NC + c] = s;
        if (s > bv) { bv = s; bc = c; }
    }
    __shared__ float rv[256];
    __shared__ int   ri[256];
    rv[threadIdx.x] = bv; ri[threadIdx.x] = bc;
    __syncthreads();
    for (int s = 128; s; s >>= 1) {
        if (threadIdx.x < s) {
            float ov = rv[threadIdx.x + s]; int oi = ri[threadIdx.x + s];
            if (ov > rv[threadIdx.x] ||
                (ov == rv[threadIdx.x] && oi < ri[threadIdx.x])) {
                rv[threadIdx.x] = ov; ri[threadIdx.x] = oi;
            }
        }
        __syncthreads();
    }
    if (threadIdx.x == 0) out_labels[row] = (float)ri[0];
}

// ---------------- grads: mean of 8 gathered bank_features rows ----------------
__global__ __launch_bounds__(256) void grads_kernel(
    const float* __restrict__ bank, const int* __restrict__ idxs,
    float* __restrict__ out_grads)
{
    int row = blockIdx.x;
    __shared__ int id[KSEL];
    if (threadIdx.x < KSEL) id[threadIdx.x] = idxs[row * KSEL + threadIdx.x];
    __syncthreads();
    for (int c = threadIdx.x; c < DIM / 4; c += 256) {
        float4 acc = {0.f, 0.f, 0.f, 0.f};
        #pragma unroll
        for (int k = 0; k < KSEL; ++k) {
            float4 t = ((const float4*)(bank + (size_t)id[k] * DIM))[c];
            acc.x += t.x; acc.y += t.y; acc.z += t.z; acc.w += t.w;
        }
        float4 o = {acc.x * 0.125f, acc.y * 0.125f, acc.z * 0.125f, acc.w * 0.125f};
        ((float4*)(out_grads + (size_t)row * DIM))[c] = o;
    }
}

// ---------------- pred_images: mean of 8 gathered images ----------------------
// L3-tiled: 49 column-tiles (tile = slowest grid dim). Per-tile unique
// footprint = 2048 images x 12 KB = 25 MB << 256 MB L3; even with ~1.4 tiles
// of blocks concurrently resident the working set is ~60 MB, so image
// re-references (~4x each) should nearly always hit Infinity Cache.
// Non-temporal output stores keep the 0.6 GB write stream out of L3.
#define ITILES 49
#define CBS    1            // col-blocks per tile; 49*1=49 col-blocks total
#define V4PT   3            // float4 per thread; block covers 3*256=768 float4
// 49 col-blocks * 768 float4 = 37632 = IMG4  ✓

__global__ __launch_bounds__(256) void images_kernel(
    const float* __restrict__ image_bank, const int* __restrict__ idxs,
    float* __restrict__ out_images)
{
    const int bid  = blockIdx.x;
    const int tile = bid / (CBS * NF);
    const int rem  = bid % (CBS * NF);
    const int row  = rem / CBS;
    const int cb   = rem % CBS;
    const int base4 = (tile * CBS + cb) * (V4PT * 256) + threadIdx.x;

    __shared__ int id[KSEL];
    if (threadIdx.x < KSEL) id[threadIdx.x] = idxs[row * KSEL + threadIdx.x];
    __syncthreads();

    const f32x4* __restrict__ bank4 = (const f32x4*)image_bank;
    f32x4* out4 = (f32x4*)(out_images + (size_t)row * IMG) + base4;

    const f32x4* p[KSEL];
    #pragma unroll
    for (int k = 0; k < KSEL; ++k)
        p[k] = bank4 + (size_t)id[k] * IMG4 + base4;

    f32x4 t[V4PT][KSEL];
    #pragma unroll
    for (int v = 0; v < V4PT; ++v)
        #pragma unroll
        for (int k = 0; k < KSEL; ++k)
            t[v][k] = p[k][v * 256];

    #pragma unroll
    for (int v = 0; v < V4PT; ++v) {
        f32x4 s01 = t[v][0] + t[v][1];
        f32x4 s23 = t[v][2] + t[v][3];
        f32x4 s45 = t[v][4] + t[v][5];
        f32x4 s67 = t[v][6] + t[v][7];
        f32x4 o = ((s01 + s23) + (s45 + s67)) * 0.125f;
        __builtin_nontemporal_store(o, out4 + v * 256);
    }
}

extern "C" void kernel_launch(void* const* d_in, const int* in_sizes, int n_in,
                              void* d_out, int out_size, void* d_ws, size_t ws_size,
                              hipStream_t stream)
{
    const float* feats      = (const float*)d_in[0];
    const float* bank_feats = (const float*)d_in[1];
    const float* bank_probs = (const float*)d_in[2];
    const float* image_bank = (const float*)d_in[3];

    float* out = (float*)d_out;
    // output layout: labels[1024] | probs[1024*1000] | images[1024*150528] | grads[1024*2048]
    float* out_labels = out;
    float* out_probs  = out + NF;
    float* out_images = out + NF + (size_t)NF * NC;
    float* out_grads  = out + NF + (size_t)NF * NC + (size_t)NF * IMG;

    // dist matrix scratch lives inside the pred_images output region (it is
    // fully overwritten by images_kernel, which runs last) — deterministic.
    float* dist = out_images;

    // small scratch in d_ws: invf[NF] | invb[NB] | idxs[NF*KSEL] (~45 KB)
    float* invf = (float*)d_ws;
    float* invb = invf + NF;
    int*   idxs = (int*)(invb + NB);

    norms_kernel<<<NF + NB, 256, 0, stream>>>(feats, bank_feats, invf, invb);

    dim3 ggrid(NB / GBN, NF / GBM);   // (32, 8) = 256 workgroups
    dist_kernel<<<ggrid, 256, 0, stream>>>(feats, bank_feats, invf, invb, dist);

    topk_kernel<<<NF, 256, 0, stream>>>(dist, idxs);

    probs_kernel<<<NF, 256, 0, stream>>>(bank_probs, idxs, out_labels, out_probs);

    grads_kernel<<<NF, 256, 0, stream>>>(bank_feats, idxs, out_grads);

    // runs last: overwrites the dist scratch with the real pred_images
    images_kernel<<<ITILES * CBS * NF, 256, 0, stream>>>(image_bank, idxs, out_images);
}

// Round 6
// 868.373 us; speedup vs baseline: 1.4183x; 1.0539x over previous
//
#include <hip/hip_runtime.h>
#include <math.h>

#define NF   1024
#define NB   2048
#define DIM  2048
#define NC   1000
#define IMG  150528   // 3*224*224, = 37632 float4
#define IMG4 37632
#define KSEL 8

typedef float f32x4 __attribute__((ext_vector_type(4)));
typedef float f32x2 __attribute__((ext_vector_type(2)));

// ---------------- norms: 1/max(||row||,eps) for feats and bank ----------------
__global__ __launch_bounds__(256) void norms_kernel(
    const float* __restrict__ feats, const float* __restrict__ bank,
    float* __restrict__ invf, float* __restrict__ invb)
{
    int row = blockIdx.x;
    const float* src;
    float* dst;
    if (row < NF) { src = feats + (size_t)row * DIM; dst = invf + row; }
    else          { src = bank  + (size_t)(row - NF) * DIM; dst = invb + (row - NF); }

    float s = 0.f;
    for (int c = threadIdx.x; c < DIM / 4; c += 256) {
        float4 v = ((const float4*)src)[c];
        s += v.x * v.x + v.y * v.y + v.z * v.z + v.w * v.w;
    }
    __shared__ float red[4];
    for (int off = 32; off; off >>= 1) s += __shfl_down(s, off, 64);
    if ((threadIdx.x & 63) == 0) red[threadIdx.x >> 6] = s;
    __syncthreads();
    if (threadIdx.x == 0) {
        float t = red[0] + red[1] + red[2] + red[3];
        float n = fmaxf(sqrtf(t), 1e-12f);
        *dst = 1.0f / n;
    }
}

// ------ dist GEMM: dist[i][j] = 1 - (A_i . B_j) * invf[i] * invb[j] ----------
// 128x64 tile -> 256 workgroups (one per CU). Inner math is f32x2 packed
// (v_pk_fma_f32: 2 f32 FMA/lane/2cy -> 157 TF path; scalar caps at 78.6).
// Double-buffered LDS: one barrier per K-step; next tile's global loads are
// issued before the compute so they stay in flight under the MAC loop.
#define GBM 128
#define GBN 64
#define GBK 16

__global__ __launch_bounds__(256) void dist_kernel(
    const float* __restrict__ A, const float* __restrict__ B,
    const float* __restrict__ invf, const float* __restrict__ invb,
    float* __restrict__ dist)
{
    __shared__ float As[2][GBK][GBM];   // k-major
    __shared__ float Bs[2][GBK][GBN];

    const int tid  = threadIdx.x;
    const int brow = blockIdx.y * GBM;   // over NF
    const int bcol = blockIdx.x * GBN;   // over NB
    const int ty   = tid >> 4;           // 0..15 -> rows ty*8..+7
    const int tx   = tid & 15;           // 0..15 -> cols tx*4..+3

    const int lrow = tid >> 2;           // 0..63
    const int lk   = (tid & 3) * 4;      // 0,4,8,12

    f32x2 acc01[8] = {};
    f32x2 acc23[8] = {};

    // prologue: stage tile 0
    {
        float4 a0 = *(const float4*)(A + (size_t)(brow + lrow)      * DIM + lk);
        float4 a1 = *(const float4*)(A + (size_t)(brow + lrow + 64) * DIM + lk);
        float4 b0 = *(const float4*)(B + (size_t)(bcol + lrow)      * DIM + lk);
        As[0][lk + 0][lrow] = a0.x; As[0][lk + 1][lrow] = a0.y;
        As[0][lk + 2][lrow] = a0.z; As[0][lk + 3][lrow] = a0.w;
        As[0][lk + 0][lrow + 64] = a1.x; As[0][lk + 1][lrow + 64] = a1.y;
        As[0][lk + 2][lrow + 64] = a1.z; As[0][lk + 3][lrow + 64] = a1.w;
        Bs[0][lk + 0][lrow] = b0.x; Bs[0][lk + 1][lrow] = b0.y;
        Bs[0][lk + 2][lrow] = b0.z; Bs[0][lk + 3][lrow] = b0.w;
    }
    __syncthreads();

    int cur = 0;
    for (int k0 = 0; k0 < DIM; k0 += GBK) {
        const bool has_next = (k0 + GBK) < DIM;
        float4 na0, na1, nb0;
        if (has_next) {   // issue next tile's global loads (in flight under MACs)
            na0 = *(const float4*)(A + (size_t)(brow + lrow)      * DIM + k0 + GBK + lk);
            na1 = *(const float4*)(A + (size_t)(brow + lrow + 64) * DIM + k0 + GBK + lk);
            nb0 = *(const float4*)(B + (size_t)(bcol + lrow)      * DIM + k0 + GBK + lk);
        }

        #pragma unroll
        for (int k = 0; k < GBK; ++k) {
            float4 av0 = *(const float4*)&As[cur][k][ty * 8];
            float4 av1 = *(const float4*)&As[cur][k][ty * 8 + 4];
            f32x2 b01 = *(const f32x2*)&Bs[cur][k][tx * 4];
            f32x2 b23 = *(const f32x2*)&Bs[cur][k][tx * 4 + 2];
            float a[8] = {av0.x, av0.y, av0.z, av0.w, av1.x, av1.y, av1.z, av1.w};
            #pragma unroll
            for (int i = 0; i < 8; ++i) {
                f32x2 ai = {a[i], a[i]};
                acc01[i] = __builtin_elementwise_fma(ai, b01, acc01[i]);
                acc23[i] = __builtin_elementwise_fma(ai, b23, acc23[i]);
            }
        }

        if (has_next) {
            const int nxt = cur ^ 1;
            As[nxt][lk + 0][lrow] = na0.x; As[nxt][lk + 1][lrow] = na0.y;
            As[nxt][lk + 2][lrow] = na0.z; As[nxt][lk + 3][lrow] = na0.w;
            As[nxt][lk + 0][lrow + 64] = na1.x; As[nxt][lk + 1][lrow + 64] = na1.y;
            As[nxt][lk + 2][lrow + 64] = na1.z; As[nxt][lk + 3][lrow + 64] = na1.w;
            Bs[nxt][lk + 0][lrow] = nb0.x; Bs[nxt][lk + 1][lrow] = nb0.y;
            Bs[nxt][lk + 2][lrow] = nb0.z; Bs[nxt][lk + 3][lrow] = nb0.w;
        }
        __syncthreads();
        cur ^= 1;
    }

    float fi[8], fb[4];
    #pragma unroll
    for (int i = 0; i < 8; ++i) fi[i] = invf[brow + ty * 8 + i];
    #pragma unroll
    for (int j = 0; j < 4; ++j) fb[j] = invb[bcol + tx * 4 + j];
    #pragma unroll
    for (int i = 0; i < 8; ++i) {
        size_t ro = (size_t)(brow + ty * 8 + i) * NB + bcol + tx * 4;
        float4 o;
        o.x = 1.0f - acc01[i].x * fi[i] * fb[0];
        o.y = 1.0f - acc01[i].y * fi[i] * fb[1];
        o.z = 1.0f - acc23[i].x * fi[i] * fb[2];
        o.w = 1.0f - acc23[i].y * fi[i] * fb[3];
        *(float4*)(dist + ro) = o;
    }
}

// ---------------- top-8 per row (descending, ties -> lower index) -------------
__global__ __launch_bounds__(256) void topk_kernel(
    const float* __restrict__ dist, int* __restrict__ idxs)
{
    __shared__ float v[NB];
    __shared__ float rv[256];
    __shared__ int   ri[256];
    int row = blockIdx.x;
    const float* src = dist + (size_t)row * NB;
    for (int c = threadIdx.x; c < NB; c += 256) v[c] = src[c];
    __syncthreads();

    for (int sel = 0; sel < KSEL; ++sel) {
        float bv = -1e30f; int bi = NB;
        for (int c = threadIdx.x; c < NB; c += 256) {
            float x = v[c];
            if (x > bv) { bv = x; bi = c; }   // c increasing: first max kept
        }
        rv[threadIdx.x] = bv; ri[threadIdx.x] = bi;
        __syncthreads();
        for (int s = 128; s; s >>= 1) {
            if (threadIdx.x < s) {
                float ov = rv[threadIdx.x + s]; int oi = ri[threadIdx.x + s];
                if (ov > rv[threadIdx.x] ||
                    (ov == rv[threadIdx.x] && oi < ri[threadIdx.x])) {
                    rv[threadIdx.x] = ov; ri[threadIdx.x] = oi;
                }
            }
            __syncthreads();
        }
        if (threadIdx.x == 0) { idxs[row * KSEL + sel] = ri[0]; v[ri[0]] = -1e30f; }
        __syncthreads();
    }
}

// ---------------- pred_probs (mean of 8 gathered rows) + argmax label ---------
__global__ __launch_bounds__(256) void probs_kernel(
    const float* __restrict__ bank_probs, const int* __restrict__ idxs,
    float* __restrict__ out_labels, float* __restrict__ out_probs)
{
    int row = blockIdx.x;
    __shared__ int id[KSEL];
    if (threadIdx.x < KSEL) id[threadIdx.x] = idxs[row * KSEL + threadIdx.x];
    __syncthreads();

    float bv = -1e30f; int bc = NC;
    for (int c = threadIdx.x; c < NC; c += 256) {
        float s = 0.f;
        #pragma unroll
        for (int k = 0; k < KSEL; ++k) s += bank_probs[(size_t)id[k] * NC + c];
        s *= (1.0f / KSEL);
        out_probs[(size_t)row * NC + c] = s;
        if (s > bv) { bv = s; bc = c; }
    }
    __shared__ float rv[256];
    __shared__ int   ri[256];
    rv[threadIdx.x] = bv; ri[threadIdx.x] = bc;
    __syncthreads();
    for (int s = 128; s; s >>= 1) {
        if (threadIdx.x < s) {
            float ov = rv[threadIdx.x + s]; int oi = ri[threadIdx.x + s];
            if (ov > rv[threadIdx.x] ||
                (ov == rv[threadIdx.x] && oi < ri[threadIdx.x])) {
                rv[threadIdx.x] = ov; ri[threadIdx.x] = oi;
            }
        }
        __syncthreads();
    }
    if (threadIdx.x == 0) out_labels[row] = (float)ri[0];
}

// ---------------- grads: mean of 8 gathered bank_features rows ----------------
__global__ __launch_bounds__(256) void grads_kernel(
    const float* __restrict__ bank, const int* __restrict__ idxs,
    float* __restrict__ out_grads)
{
    int row = blockIdx.x;
    __shared__ int id[KSEL];
    if (threadIdx.x < KSEL) id[threadIdx.x] = idxs[row * KSEL + threadIdx.x];
    __syncthreads();
    for (int c = threadIdx.x; c < DIM / 4; c += 256) {
        float4 acc = {0.f, 0.f, 0.f, 0.f};
        #pragma unroll
        for (int k = 0; k < KSEL; ++k) {
            float4 t = ((const float4*)(bank + (size_t)id[k] * DIM))[c];
            acc.x += t.x; acc.y += t.y; acc.z += t.z; acc.w += t.w;
        }
        float4 o = {acc.x * 0.125f, acc.y * 0.125f, acc.z * 0.125f, acc.w * 0.125f};
        ((float4*)(out_grads + (size_t)row * DIM))[c] = o;
    }
}

// ---------------- pred_images: mean of 8 gathered images ----------------------
// L3-tiled: 49 column-tiles (tile = slowest grid dim); per-tile unique
// footprint 2048 x 12 KB = 25 MB << 256 MB L3.
// TWO rows per block: per v-iteration, 16 independent gather loads (both
// rows) are issued and pinned ahead of the reductions by sched_barrier(0),
// so row-0's reduce waits at vmcnt(8) while row-1's 8 loads stay in flight
// (double the per-wave MLP the compiler allowed before).
// Non-temporal output stores keep the 0.6 GB write stream out of L3.
#define ITILES 49
#define V4PT   3            // float4 per thread; block covers 3*256=768 float4
// 49 col-blocks * 768 float4 = 37632 = IMG4  ✓

__global__ __launch_bounds__(256) void images_kernel(
    const float* __restrict__ image_bank, const int* __restrict__ idxs,
    float* __restrict__ out_images)
{
    const int bid  = blockIdx.x;
    const int tile = bid / (NF / 2);
    const int rem  = bid % (NF / 2);
    const int row0 = rem * 2;
    const int row1 = rem * 2 + 1;
    const int base4 = tile * (V4PT * 256) + threadIdx.x;

    __shared__ int id[2 * KSEL];
    if (threadIdx.x < 2 * KSEL) id[threadIdx.x] = idxs[row0 * KSEL + threadIdx.x];
    __syncthreads();

    const f32x4* __restrict__ bank4 = (const f32x4*)image_bank;
    f32x4* out0 = (f32x4*)(out_images + (size_t)row0 * IMG) + base4;
    f32x4* out1 = (f32x4*)(out_images + (size_t)row1 * IMG) + base4;

    const f32x4* p0[KSEL];
    const f32x4* p1[KSEL];
    #pragma unroll
    for (int k = 0; k < KSEL; ++k) {
        p0[k] = bank4 + (size_t)id[k]        * IMG4 + base4;
        p1[k] = bank4 + (size_t)id[k + KSEL] * IMG4 + base4;
    }

    #pragma unroll
    for (int v = 0; v < V4PT; ++v) {
        f32x4 t0[KSEL], t1[KSEL];
        #pragma unroll
        for (int k = 0; k < KSEL; ++k) t0[k] = p0[k][v * 256];
        #pragma unroll
        for (int k = 0; k < KSEL; ++k) t1[k] = p1[k][v * 256];
        __builtin_amdgcn_sched_barrier(0);   // pin: all 16 loads issued first

        f32x4 a01 = t0[0] + t0[1], a23 = t0[2] + t0[3];
        f32x4 a45 = t0[4] + t0[5], a67 = t0[6] + t0[7];
        f32x4 o0 = ((a01 + a23) + (a45 + a67)) * 0.125f;
        __builtin_nontemporal_store(o0, out0 + v * 256);

        f32x4 b01 = t1[0] + t1[1], b23 = t1[2] + t1[3];
        f32x4 b45 = t1[4] + t1[5], b67 = t1[6] + t1[7];
        f32x4 o1 = ((b01 + b23) + (b45 + b67)) * 0.125f;
        __builtin_nontemporal_store(o1, out1 + v * 256);
    }
}

extern "C" void kernel_launch(void* const* d_in, const int* in_sizes, int n_in,
                              void* d_out, int out_size, void* d_ws, size_t ws_size,
                              hipStream_t stream)
{
    const float* feats      = (const float*)d_in[0];
    const float* bank_feats = (const float*)d_in[1];
    const float* bank_probs = (const float*)d_in[2];
    const float* image_bank = (const float*)d_in[3];

    float* out = (float*)d_out;
    // output layout: labels[1024] | probs[1024*1000] | images[1024*150528] | grads[1024*2048]
    float* out_labels = out;
    float* out_probs  = out + NF;
    float* out_images = out + NF + (size_t)NF * NC;
    float* out_grads  = out + NF + (size_t)NF * NC + (size_t)NF * IMG;

    // dist matrix scratch lives inside the pred_images output region (it is
    // fully overwritten by images_kernel, which runs last) — deterministic.
    float* dist = out_images;

    // small scratch in d_ws: invf[NF] | invb[NB] | idxs[NF*KSEL] (~45 KB)
    float* invf = (float*)d_ws;
    float* invb = invf + NF;
    int*   idxs = (int*)(invb + NB);

    norms_kernel<<<NF + NB, 256, 0, stream>>>(feats, bank_feats, invf, invb);

    dim3 ggrid(NB / GBN, NF / GBM);   // (32, 8) = 256 workgroups
    dist_kernel<<<ggrid, 256, 0, stream>>>(feats, bank_feats, invf, invb, dist);

    topk_kernel<<<NF, 256, 0, stream>>>(dist, idxs);

    probs_kernel<<<NF, 256, 0, stream>>>(bank_probs, idxs, out_labels, out_probs);

    grads_kernel<<<NF, 256, 0, stream>>>(bank_feats, idxs, out_grads);

    // runs last: overwrites the dist scratch with the real pred_images
    images_kernel<<<ITILES * (NF / 2), 256, 0, stream>>>(image_bank, idxs, out_images);
}

// Round 7
// 795.527 us; speedup vs baseline: 1.5482x; 1.0916x over previous
//
#include <hip/hip_runtime.h>
#include <math.h>

#define NF   1024
#define NB   2048
#define DIM  2048
#define NC   1000
#define IMG  150528   // 3*224*224, = 37632 float4
#define IMG4 37632
#define KSEL 8

typedef float f32x4 __attribute__((ext_vector_type(4)));
typedef float f32x2 __attribute__((ext_vector_type(2)));

// ---------------- norms: 1/max(||row||,eps) for feats and bank ----------------
__global__ __launch_bounds__(256) void norms_kernel(
    const float* __restrict__ feats, const float* __restrict__ bank,
    float* __restrict__ invf, float* __restrict__ invb)
{
    int row = blockIdx.x;
    const float* src;
    float* dst;
    if (row < NF) { src = feats + (size_t)row * DIM; dst = invf + row; }
    else          { src = bank  + (size_t)(row - NF) * DIM; dst = invb + (row - NF); }

    float s = 0.f;
    for (int c = threadIdx.x; c < DIM / 4; c += 256) {
        float4 v = ((const float4*)src)[c];
        s += v.x * v.x + v.y * v.y + v.z * v.z + v.w * v.w;
    }
    __shared__ float red[4];
    for (int off = 32; off; off >>= 1) s += __shfl_down(s, off, 64);
    if ((threadIdx.x & 63) == 0) red[threadIdx.x >> 6] = s;
    __syncthreads();
    if (threadIdx.x == 0) {
        float t = red[0] + red[1] + red[2] + red[3];
        float n = fmaxf(sqrtf(t), 1e-12f);
        *dst = 1.0f / n;
    }
}

// ------ dist GEMM: dist[i][j] = 1 - (A_i . B_j) * invf[i] * invb[j] ----------
// 128x64 tile -> 256 workgroups (one per CU). f32x2 packed FMA + double-
// buffered LDS (one barrier per K-step; next tile's global loads in flight
// under the MAC loop). Near the 157 TF f32 issue ceiling for this structure.
#define GBM 128
#define GBN 64
#define GBK 16

__global__ __launch_bounds__(256) void dist_kernel(
    const float* __restrict__ A, const float* __restrict__ B,
    const float* __restrict__ invf, const float* __restrict__ invb,
    float* __restrict__ dist)
{
    __shared__ float As[2][GBK][GBM];   // k-major
    __shared__ float Bs[2][GBK][GBN];

    const int tid  = threadIdx.x;
    const int brow = blockIdx.y * GBM;   // over NF
    const int bcol = blockIdx.x * GBN;   // over NB
    const int ty   = tid >> 4;           // 0..15 -> rows ty*8..+7
    const int tx   = tid & 15;           // 0..15 -> cols tx*4..+3

    const int lrow = tid >> 2;           // 0..63
    const int lk   = (tid & 3) * 4;      // 0,4,8,12

    f32x2 acc01[8] = {};
    f32x2 acc23[8] = {};

    // prologue: stage tile 0
    {
        float4 a0 = *(const float4*)(A + (size_t)(brow + lrow)      * DIM + lk);
        float4 a1 = *(const float4*)(A + (size_t)(brow + lrow + 64) * DIM + lk);
        float4 b0 = *(const float4*)(B + (size_t)(bcol + lrow)      * DIM + lk);
        As[0][lk + 0][lrow] = a0.x; As[0][lk + 1][lrow] = a0.y;
        As[0][lk + 2][lrow] = a0.z; As[0][lk + 3][lrow] = a0.w;
        As[0][lk + 0][lrow + 64] = a1.x; As[0][lk + 1][lrow + 64] = a1.y;
        As[0][lk + 2][lrow + 64] = a1.z; As[0][lk + 3][lrow + 64] = a1.w;
        Bs[0][lk + 0][lrow] = b0.x; Bs[0][lk + 1][lrow] = b0.y;
        Bs[0][lk + 2][lrow] = b0.z; Bs[0][lk + 3][lrow] = b0.w;
    }
    __syncthreads();

    int cur = 0;
    for (int k0 = 0; k0 < DIM; k0 += GBK) {
        const bool has_next = (k0 + GBK) < DIM;
        float4 na0, na1, nb0;
        if (has_next) {   // issue next tile's global loads (in flight under MACs)
            na0 = *(const float4*)(A + (size_t)(brow + lrow)      * DIM + k0 + GBK + lk);
            na1 = *(const float4*)(A + (size_t)(brow + lrow + 64) * DIM + k0 + GBK + lk);
            nb0 = *(const float4*)(B + (size_t)(bcol + lrow)      * DIM + k0 + GBK + lk);
        }

        #pragma unroll
        for (int k = 0; k < GBK; ++k) {
            float4 av0 = *(const float4*)&As[cur][k][ty * 8];
            float4 av1 = *(const float4*)&As[cur][k][ty * 8 + 4];
            f32x2 b01 = *(const f32x2*)&Bs[cur][k][tx * 4];
            f32x2 b23 = *(const f32x2*)&Bs[cur][k][tx * 4 + 2];
            float a[8] = {av0.x, av0.y, av0.z, av0.w, av1.x, av1.y, av1.z, av1.w};
            #pragma unroll
            for (int i = 0; i < 8; ++i) {
                f32x2 ai = {a[i], a[i]};
                acc01[i] = __builtin_elementwise_fma(ai, b01, acc01[i]);
                acc23[i] = __builtin_elementwise_fma(ai, b23, acc23[i]);
            }
        }

        if (has_next) {
            const int nxt = cur ^ 1;
            As[nxt][lk + 0][lrow] = na0.x; As[nxt][lk + 1][lrow] = na0.y;
            As[nxt][lk + 2][lrow] = na0.z; As[nxt][lk + 3][lrow] = na0.w;
            As[nxt][lk + 0][lrow + 64] = na1.x; As[nxt][lk + 1][lrow + 64] = na1.y;
            As[nxt][lk + 2][lrow + 64] = na1.z; As[nxt][lk + 3][lrow + 64] = na1.w;
            Bs[nxt][lk + 0][lrow] = nb0.x; Bs[nxt][lk + 1][lrow] = nb0.y;
            Bs[nxt][lk + 2][lrow] = nb0.z; Bs[nxt][lk + 3][lrow] = nb0.w;
        }
        __syncthreads();
        cur ^= 1;
    }

    float fi[8], fb[4];
    #pragma unroll
    for (int i = 0; i < 8; ++i) fi[i] = invf[brow + ty * 8 + i];
    #pragma unroll
    for (int j = 0; j < 4; ++j) fb[j] = invb[bcol + tx * 4 + j];
    #pragma unroll
    for (int i = 0; i < 8; ++i) {
        size_t ro = (size_t)(brow + ty * 8 + i) * NB + bcol + tx * 4;
        float4 o;
        o.x = 1.0f - acc01[i].x * fi[i] * fb[0];
        o.y = 1.0f - acc01[i].y * fi[i] * fb[1];
        o.z = 1.0f - acc23[i].x * fi[i] * fb[2];
        o.w = 1.0f - acc23[i].y * fi[i] * fb[3];
        *(float4*)(dist + ro) = o;
    }
}

// ---------------- top-8 per row (descending, ties -> lower index) -------------
__global__ __launch_bounds__(256) void topk_kernel(
    const float* __restrict__ dist, int* __restrict__ idxs)
{
    __shared__ float v[NB];
    __shared__ float rv[256];
    __shared__ int   ri[256];
    int row = blockIdx.x;
    const float* src = dist + (size_t)row * NB;
    for (int c = threadIdx.x; c < NB; c += 256) v[c] = src[c];
    __syncthreads();

    for (int sel = 0; sel < KSEL; ++sel) {
        float bv = -1e30f; int bi = NB;
        for (int c = threadIdx.x; c < NB; c += 256) {
            float x = v[c];
            if (x > bv) { bv = x; bi = c; }   // c increasing: first max kept
        }
        rv[threadIdx.x] = bv; ri[threadIdx.x] = bi;
        __syncthreads();
        for (int s = 128; s; s >>= 1) {
            if (threadIdx.x < s) {
                float ov = rv[threadIdx.x + s]; int oi = ri[threadIdx.x + s];
                if (ov > rv[threadIdx.x] ||
                    (ov == rv[threadIdx.x] && oi < ri[threadIdx.x])) {
                    rv[threadIdx.x] = ov; ri[threadIdx.x] = oi;
                }
            }
            __syncthreads();
        }
        if (threadIdx.x == 0) { idxs[row * KSEL + sel] = ri[0]; v[ri[0]] = -1e30f; }
        __syncthreads();
    }
}

// ---------------- pred_probs (mean of 8 gathered rows) + argmax label ---------
__global__ __launch_bounds__(256) void probs_kernel(
    const float* __restrict__ bank_probs, const int* __restrict__ idxs,
    float* __restrict__ out_labels, float* __restrict__ out_probs)
{
    int row = blockIdx.x;
    __shared__ int id[KSEL];
    if (threadIdx.x < KSEL) id[threadIdx.x] = idxs[row * KSEL + threadIdx.x];
    __syncthreads();

    float bv = -1e30f; int bc = NC;
    for (int c = threadIdx.x; c < NC; c += 256) {
        float s = 0.f;
        #pragma unroll
        for (int k = 0; k < KSEL; ++k) s += bank_probs[(size_t)id[k] * NC + c];
        s *= (1.0f / KSEL);
        out_probs[(size_t)row * NC + c] = s;
        if (s > bv) { bv = s; bc = c; }
    }
    __shared__ float rv[256];
    __shared__ int   ri[256];
    rv[threadIdx.x] = bv; ri[threadIdx.x] = bc;
    __syncthreads();
    for (int s = 128; s; s >>= 1) {
        if (threadIdx.x < s) {
            float ov = rv[threadIdx.x + s]; int oi = ri[threadIdx.x + s];
            if (ov > rv[threadIdx.x] ||
                (ov == rv[threadIdx.x] && oi < ri[threadIdx.x])) {
                rv[threadIdx.x] = ov; ri[threadIdx.x] = oi;
            }
        }
        __syncthreads();
    }
    if (threadIdx.x == 0) out_labels[row] = (float)ri[0];
}

// ---------------- grads: mean of 8 gathered bank_features rows ----------------
__global__ __launch_bounds__(256) void grads_kernel(
    const float* __restrict__ bank, const int* __restrict__ idxs,
    float* __restrict__ out_grads)
{
    int row = blockIdx.x;
    __shared__ int id[KSEL];
    if (threadIdx.x < KSEL) id[threadIdx.x] = idxs[row * KSEL + threadIdx.x];
    __syncthreads();
    for (int c = threadIdx.x; c < DIM / 4; c += 256) {
        float4 acc = {0.f, 0.f, 0.f, 0.f};
        #pragma unroll
        for (int k = 0; k < KSEL; ++k) {
            float4 t = ((const float4*)(bank + (size_t)id[k] * DIM))[c];
            acc.x += t.x; acc.y += t.y; acc.z += t.z; acc.w += t.w;
        }
        float4 o = {acc.x * 0.125f, acc.y * 0.125f, acc.z * 0.125f, acc.w * 0.125f};
        ((float4*)(out_grads + (size_t)row * DIM))[c] = o;
    }
}

// ---------------- pred_images: mean of 8 gathered images ----------------------
// L3-tiled: 147 column-tiles (tile = slowest grid dim); per-tile unique
// footprint 2048 x 4 KB = 8 MB; ~3 tiles concurrently resident = ~24 MB
// working set << 256 MB L3.
// FOUR rows per block, V4PT=1: idxs are read through a uniform pointer so
// the 32 gather bases become SGPRs (s_load) — no VGPR pointer array for the
// compiler to sink. All 32 independent global_load_dwordx4 are issued and
// pinned ahead of the reductions (sched_barrier(0)); row-0's reduce waits at
// vmcnt(24), keeping 24+ loads in flight per wave (4x previous depth).
// Non-temporal output stores keep the 0.6 GB write stream out of L3.
#define ITILES 147   // 147 tiles * 256 float4 = 37632 = IMG4  ✓
#define RPB    4     // rows per block

__global__ __launch_bounds__(256) void images_kernel(
    const float* __restrict__ image_bank, const int* __restrict__ idxs,
    float* __restrict__ out_images)
{
    const int bid  = blockIdx.x;
    const int tile = bid / (NF / RPB);
    const int rem  = bid % (NF / RPB);
    const int row0 = rem * RPB;
    const int base4 = tile * 256 + threadIdx.x;

    const int* __restrict__ ip = idxs + row0 * KSEL;   // block-uniform -> s_load
    const f32x4* __restrict__ bank4 = (const f32x4*)image_bank;

    f32x4 t[RPB][KSEL];
    #pragma unroll
    for (int r = 0; r < RPB; ++r)
        #pragma unroll
        for (int k = 0; k < KSEL; ++k)
            t[r][k] = bank4[(size_t)ip[r * KSEL + k] * IMG4 + base4];
    __builtin_amdgcn_sched_barrier(0);   // pin: all 32 loads issued first

    #pragma unroll
    for (int r = 0; r < RPB; ++r) {
        f32x4 s01 = t[r][0] + t[r][1];
        f32x4 s23 = t[r][2] + t[r][3];
        f32x4 s45 = t[r][4] + t[r][5];
        f32x4 s67 = t[r][6] + t[r][7];
        f32x4 o = ((s01 + s23) + (s45 + s67)) * 0.125f;
        f32x4* outp = (f32x4*)(out_images + (size_t)(row0 + r) * IMG) + base4;
        __builtin_nontemporal_store(o, outp);
    }
}

extern "C" void kernel_launch(void* const* d_in, const int* in_sizes, int n_in,
                              void* d_out, int out_size, void* d_ws, size_t ws_size,
                              hipStream_t stream)
{
    const float* feats      = (const float*)d_in[0];
    const float* bank_feats = (const float*)d_in[1];
    const float* bank_probs = (const float*)d_in[2];
    const float* image_bank = (const float*)d_in[3];

    float* out = (float*)d_out;
    // output layout: labels[1024] | probs[1024*1000] | images[1024*150528] | grads[1024*2048]
    float* out_labels = out;
    float* out_probs  = out + NF;
    float* out_images = out + NF + (size_t)NF * NC;
    float* out_grads  = out + NF + (size_t)NF * NC + (size_t)NF * IMG;

    // dist matrix scratch lives inside the pred_images output region (it is
    // fully overwritten by images_kernel, which runs last) — deterministic.
    float* dist = out_images;

    // small scratch in d_ws: invf[NF] | invb[NB] | idxs[NF*KSEL] (~45 KB)
    float* invf = (float*)d_ws;
    float* invb = invf + NF;
    int*   idxs = (int*)(invb + NB);

    norms_kernel<<<NF + NB, 256, 0, stream>>>(feats, bank_feats, invf, invb);

    dim3 ggrid(NB / GBN, NF / GBM);   // (32, 8) = 256 workgroups
    dist_kernel<<<ggrid, 256, 0, stream>>>(feats, bank_feats, invf, invb, dist);

    topk_kernel<<<NF, 256, 0, stream>>>(dist, idxs);

    probs_kernel<<<NF, 256, 0, stream>>>(bank_probs, idxs, out_labels, out_probs);

    grads_kernel<<<NF, 256, 0, stream>>>(bank_feats, idxs, out_grads);

    // runs last: overwrites the dist scratch with the real pred_images
    images_kernel<<<ITILES * (NF / RPB), 256, 0, stream>>>(image_bank, idxs, out_images);
}